// Round 9
// baseline (107.814 us; speedup 1.0000x reference)
//
#include <hip/hip_runtime.h>
#include <hip/hip_bf16.h>

// Problem: B=2, L=64, F=128. Output (B, L(a), L(t), L(s), 2F) f32 = 512 MiB.
// out[b,a,t,s,0:128]   = mask * (P[b,s]-P[b,a])/(s-a)   [sign cancels]
// out[b,a,t,s,128:256] = mask * (P[b,s]-P[b,t])/(s-t)
// mask = (a!=t)&(a!=s)&(t!=s).  Pure write-BW bound: 512 MiB out, 64 KiB in.
//
// R9 A/B vs R8 (single variable): wave w owns s = 4k+w (k=0..15) instead of
// s in [16w,16w+16). At each unrolled step the block's 4 waves write 4
// ADJACENT 1KB rows -> one 4KB contiguous burst; write-stream count drops
// 4096 -> 1024. Everything else (registers, mask logic, t-group 8, plain
// stores) identical to R8.

#define B_ 2
#define L_ 64
#define F_ 128

typedef float f32x4 __attribute__((ext_vector_type(4)));

__device__ float g_P[B_ * (L_ + 1) * F_];   // prefix sums, 66.5 KB

__global__ void prefix_kernel(const float* __restrict__ x) {
    const int b = blockIdx.x;       // 0..1
    const int f = threadIdx.x;      // 0..127
    const float* xb = x + b * L_ * F_ + f;
    float* Pb = g_P + b * (L_ + 1) * F_ + f;

    float v[L_];
#pragma unroll
    for (int r = 0; r < L_; ++r) v[r] = xb[r * F_];

    float run = 0.0f;
    Pb[0] = 0.0f;
#pragma unroll
    for (int r = 0; r < L_; ++r) {
        run += v[r];
        Pb[(r + 1) * F_] = run;
    }
}

// One block per (b, a, t-group of 8): 1024 blocks, 512 KiB contiguous each.
// 4 waves; wave w owns s = 4k + w for k = 0..15 (interleaved rows).
__global__ __launch_bounds__(256) void writer_kernel(f32x4* __restrict__ out) {
    const int bid = blockIdx.x;          // (b*64 + a)*8 + tg
    const int tg = bid & 7;
    const int a  = (bid >> 3) & 63;
    const int b  = bid >> 9;
    const int t0 = tg << 3;
    const int tid = threadIdx.x;
    const int f4 = tid & 63;             // float4 index within the 256-float row
    const int sw = tid >> 6;             // wave id 0..3

    // out index (f32x4 units): (((b*64+a)*64 + t)*64 + s)*64 + f4, s = 4k+sw
    f32x4* o = out + ((size_t)(((b << 6) + a) << 6) + t0) * 4096 + sw * 64 + f4;

    const f32x4 z = {0.f, 0.f, 0.f, 0.f};
    const bool lower = (f4 < 32);        // lanes 0..31: i=a half; 32..63: i=t half
    const float* base = g_P + ((b * (L_ + 1)) << 7) + ((f4 & 31) << 2);

    // This wave's 16 P rows (s = 4k + sw), shared across all 8 t-planes.
    f32x4 p[16];
#pragma unroll
    for (int k = 0; k < 16; ++k)
        p[k] = *reinterpret_cast<const f32x4*>(base + (((k << 2) + sw) << 7));
    const f32x4 pa = *reinterpret_cast<const f32x4*>(base + (a << 7));
    const float fa = (float)a;

#pragma unroll
    for (int tt = 0; tt < 8; ++tt) {
        const int t = t0 + tt;
        const bool plane_zero = (a == t);            // block-uniform
        // per-plane P[t]: in-loop L1-hit load (keeps live regs low)
        const f32x4 ptv = *reinterpret_cast<const f32x4*>(base + (t << 7));
        const f32x4 pi = lower ? pa : ptv;           // per-lane select
        const float fi = lower ? fa : (float)t;
        f32x4* ot = o + tt * 4096;

#pragma unroll
        for (int k = 0; k < 16; ++k) {
            const int s = (k << 2) + sw;             // wave-uniform
            f32x4 v;
            if (plane_zero || s == a || s == t) {    // wave-uniform
                v = z;
            } else {                                  // here s != i for all lanes
                const float r = __builtin_amdgcn_rcpf((float)s - fi);
                v = (p[k] - pi) * r;
            }
            ot[k * 256] = v;                          // block writes 4KB/step
        }
    }
}

extern "C" void kernel_launch(void* const* d_in, const int* in_sizes, int n_in,
                              void* d_out, int out_size, void* d_ws, size_t ws_size,
                              hipStream_t stream) {
    const float* x = (const float*)d_in[0];
    f32x4* out = (f32x4*)d_out;

    prefix_kernel<<<B_, F_, 0, stream>>>(x);
    writer_kernel<<<B_ * L_ * (L_ / 8), 256, 0, stream>>>(out);
}

// Round 10
// 99.254 us; speedup vs baseline: 1.0862x; 1.0862x over previous
//
#include <hip/hip_runtime.h>
#include <hip/hip_bf16.h>

// Problem: B=2, L=64, F=128. Output (B, L(a), L(t), L(s), 2F) f32 = 512 MiB.
// out[b,a,t,s,0:128]   = mask * (P[b,s]-P[b,a])/(s-a)   [sign cancels]
// out[b,a,t,s,128:256] = mask * (P[b,s]-P[b,t])/(s-t)
// mask = (a!=t)&(a!=s)&(t!=s); P[k] = sum x[0..k-1], P[64] never used.
// Pure write-BW bound: 512 MiB out, 64 KiB in.
//
// R10: single fused kernel, LDS-based (fixes R7's register blow-up).
// Per block: waves 0-1 rebuild P[0..63] into 32KB LDS (one column per
// thread, unroll-8 bounded pipelining), one barrier, then the proven R8
// store structure (t-group 8, contiguous 16KB per wave per plane, plain
// stores, wave-uniform mask branches). Removes the prefix dispatch and
// its graph-node serialization.

#define B_ 2
#define L_ 64
#define F_ 128

typedef float f32x4 __attribute__((ext_vector_type(4)));

// One block per (b, a, t-group of 8): 1024 blocks, 512 KiB contiguous each.
__global__ __launch_bounds__(256) void writer_kernel(f32x4* __restrict__ out,
                                                     const float* __restrict__ x) {
    const int bid = blockIdx.x;          // (b*64 + a)*8 + tg
    const int tg = bid & 7;
    const int a  = (bid >> 3) & 63;
    const int b  = bid >> 9;
    const int t0 = tg << 3;
    const int tid = threadIdx.x;

    __shared__ float Ps[L_][F_];         // 32 KB: P[0..63]

    if (tid < F_) {                      // waves 0-1: one cumsum column each
        const float* xb = x + (b << 13) + tid;   // b*L*F + column
        float run = 0.0f;
#pragma unroll 8
        for (int r = 0; r < L_; ++r) {
            Ps[r][tid] = run;            // Ps[r] = P[r] = sum x[0..r-1]
            run += xb[r << 7];
        }
    }
    __syncthreads();

    const int f4 = tid & 63;             // float4 index within the 256-float row
    const int s0 = (tid >> 6) << 4;      // this wave's first s

    // out index (f32x4 units): (((b*64+a)*64 + t)*64 + s)*64 + f4
    f32x4* o = out + ((size_t)(((b << 6) + a) << 6) + t0) * 4096 + s0 * 64 + f4;

    const f32x4 z = {0.f, 0.f, 0.f, 0.f};
    const bool lower = (f4 < 32);        // lanes 0..31: i=a half; 32..63: i=t half
    const float* base = &Ps[0][0] + ((f4 & 31) << 2);

    // Wave's s-range of P from LDS (conflict-free: 32 lanes x 16B = full row;
    // upper half-wave duplicates -> broadcast). Shared across all 8 t-planes.
    f32x4 p[16];
#pragma unroll
    for (int k = 0; k < 16; ++k)
        p[k] = *reinterpret_cast<const f32x4*>(base + ((s0 + k) << 7));
    const f32x4 pa = *reinterpret_cast<const f32x4*>(base + (a << 7));
    const float fa = (float)a;

#pragma unroll
    for (int tt = 0; tt < 8; ++tt) {
        const int t = t0 + tt;
        const bool plane_zero = (a == t);            // block-uniform
        const f32x4 ptv = *reinterpret_cast<const f32x4*>(base + (t << 7));
        const f32x4 pi = lower ? pa : ptv;           // per-lane select
        const float fi = lower ? fa : (float)t;
        f32x4* ot = o + tt * 4096;

#pragma unroll
        for (int k = 0; k < 16; ++k) {
            const int s = s0 + k;                    // wave-uniform
            f32x4 v;
            if (plane_zero || s == a || s == t) {    // wave-uniform
                v = z;
            } else {                                  // here s != i for all lanes
                const float r = __builtin_amdgcn_rcpf((float)s - fi);
                v = (p[k] - pi) * r;
            }
            ot[k * 64] = v;
        }
    }
}

extern "C" void kernel_launch(void* const* d_in, const int* in_sizes, int n_in,
                              void* d_out, int out_size, void* d_ws, size_t ws_size,
                              hipStream_t stream) {
    const float* x = (const float*)d_in[0];
    f32x4* out = (f32x4*)d_out;

    writer_kernel<<<B_ * L_ * (L_ / 8), 256, 0, stream>>>(out, x);
}